// Round 1
// baseline (748.756 us; speedup 1.0000x reference)
//
#include <hip/hip_runtime.h>
#include <hip/hip_bf16.h>
#include <math.h>

// ---------------------------------------------------------------------------
// S4D SSM fused pipeline:
//  prep_tables: f64-accurate per-(h,n) constants: w=exp(dtA), c=2*C*(w-1)/A,
//               mtab[s]=w^(64*2^s) for the cross-lane scan
//  prep_w:      W_out f32 -> bf16
//  scan:        chunked linear-recurrence scan -> y = gelu(conv(k,u)+D*u) (bf16)
//  transpose:   y (b,h,l) -> yT (b,l,h)  so GEMM B-operand is k-contiguous
//  gemm:        z = W*y + b, GLU fused epilogue out = a*sigmoid(g)
// ---------------------------------------------------------------------------

#define H_DIM 1024
#define N2_DIM 32
#define B_DIM 8
#define L_DIM 4096

typedef __attribute__((ext_vector_type(8))) short short8v;
typedef __attribute__((ext_vector_type(4))) float f32x4;

#define GLOAD16(g, l) __builtin_amdgcn_global_load_lds( \
    (const __attribute__((address_space(1))) unsigned int*)(g), \
    (__attribute__((address_space(3))) unsigned int*)(l), 16, 0, 0)

__device__ __forceinline__ unsigned short f2bf(float x) {
  unsigned int v = __float_as_uint(x);
  unsigned int r = (v + 0x7fff + ((v >> 16) & 1)) >> 16;
  return (unsigned short)r;
}

// ---------------------------------------------------------------------------
__global__ __launch_bounds__(256) void prep_tables(
    const float* __restrict__ log_dt, const float* __restrict__ C_real,
    const float* __restrict__ log_A_real, const float* __restrict__ A_imag,
    float2* __restrict__ wtab, float2* __restrict__ ctab, float2* __restrict__ mtab) {
  int idx = blockIdx.x * 256 + threadIdx.x;  // 32768 = H*N2
  int h = idx >> 5;
  double dt = exp((double)log_dt[h]);
  double Ar = -exp((double)log_A_real[idx]);
  double Ai = (double)A_imag[idx];
  double xr = dt * Ar, xi = dt * Ai;               // dtA
  double er = exp(xr);
  double wr = er * cos(xi), wi = er * sin(xi);     // w = exp(dtA)
  wtab[idx] = make_float2((float)wr, (float)wi);
  double crr = (double)C_real[2 * idx], cii = (double)C_real[2 * idx + 1];
  double nr = wr - 1.0, ni = wi;
  double den = Ar * Ar + Ai * Ai;
  double qr = (nr * Ar + ni * Ai) / den, qi = (ni * Ar - nr * Ai) / den;  // (w-1)/A
  ctab[idx] = make_float2((float)(2.0 * (crr * qr - cii * qi)),
                          (float)(2.0 * (crr * qi + cii * qr)));
#pragma unroll
  for (int s = 0; s < 6; s++) {
    double p = (double)(64 << s);
    double pr = exp(p * xr);
    mtab[idx * 6 + s] = make_float2((float)(pr * cos(p * xi)), (float)(pr * sin(p * xi)));
  }
}

// ---------------------------------------------------------------------------
__global__ __launch_bounds__(256) void prep_w(const float* __restrict__ W,
                                              unsigned short* __restrict__ Wbf) {
  int i = blockIdx.x * 256 + threadIdx.x;  // per float4, 2048*1024/4 = 524288
  float4 v = ((const float4*)W)[i];
  ushort4 o;
  o.x = f2bf(v.x); o.y = f2bf(v.y); o.z = f2bf(v.z); o.w = f2bf(v.w);
  ((ushort4*)Wbf)[i] = o;
}

// ---------------------------------------------------------------------------
// scan: one block (128 thr = 2 waves) per (b,h). Wave wv owns states
// n in [wv*16, wv*16+16). Lane j owns timesteps [j*64,(j+1)*64).
__global__ __launch_bounds__(128) void scan_kernel(
    const float* __restrict__ u, const float2* __restrict__ wtab,
    const float2* __restrict__ ctab, const float2* __restrict__ mtab,
    const float* __restrict__ D, unsigned short* __restrict__ yws) {
  __shared__ float ubuf[64][68];
  __shared__ float ybuf[2][64][68];
  int bh = blockIdx.x;
  int h = bh & (H_DIM - 1);
  int tid = threadIdx.x, lane = tid & 63, wv = tid >> 6;

  const float4* urow = (const float4*)(u + (size_t)bh * L_DIM);
#pragma unroll
  for (int it = 0; it < 8; it++) {
    int i4 = it * 128 + tid;  // 0..1023
    float4 v = urow[i4];
    *(float4*)&ubuf[i4 >> 4][(i4 & 15) * 4] = v;
  }

  float wr[16], wi[16], cr[16], ci[16];
  int nbase = h * N2_DIM + wv * 16;
#pragma unroll
  for (int nn = 0; nn < 16; nn++) {
    float2 a = wtab[nbase + nn]; wr[nn] = a.x; wi[nn] = a.y;
    float2 c = ctab[nbase + nn]; cr[nn] = c.x; ci[nn] = c.y;
  }
  __syncthreads();

  // ---- pass A: chunk-local states from zero ----
  float Sr[16], Si[16];
#pragma unroll
  for (int nn = 0; nn < 16; nn++) { Sr[nn] = 0.f; Si[nn] = 0.f; }
  for (int i4 = 0; i4 < 16; i4++) {
    float4 uv = *(float4*)&ubuf[lane][i4 * 4];
#pragma unroll
    for (int e = 0; e < 4; e++) {
      float u_ = (e == 0) ? uv.x : (e == 1) ? uv.y : (e == 2) ? uv.z : uv.w;
#pragma unroll
      for (int nn = 0; nn < 16; nn++) {
        float t = fmaf(-wi[nn], Si[nn], u_);
        float sr = fmaf(wr[nn], Sr[nn], t);
        float si = fmaf(wi[nn], Sr[nn], wr[nn] * Si[nn]);
        Sr[nn] = sr; Si[nn] = si;
      }
    }
  }

  // ---- cross-lane inclusive scan (Hillis-Steele, decay w^64 per chunk) ----
#pragma unroll
  for (int s = 0; s < 6; s++) {
    int d = 1 << s;
#pragma unroll
    for (int nn = 0; nn < 16; nn++) {
      float2 m = mtab[(nbase + nn) * 6 + s];  // w^(64*2^s), f64-accurate
      float rr = __shfl_up(Sr[nn], d, 64);
      float ri = __shfl_up(Si[nn], d, 64);
      rr = (lane >= d) ? rr : 0.f;
      ri = (lane >= d) ? ri : 0.f;
      Sr[nn] = fmaf(m.x, rr, fmaf(-m.y, ri, Sr[nn]));
      Si[nn] = fmaf(m.x, ri, fmaf(m.y, rr, Si[nn]));
    }
  }
  // exclusive shift: state at chunk start
#pragma unroll
  for (int nn = 0; nn < 16; nn++) {
    float er = __shfl_up(Sr[nn], 1, 64);
    float ei = __shfl_up(Si[nn], 1, 64);
    Sr[nn] = lane ? er : 0.f;
    Si[nn] = lane ? ei : 0.f;
  }

  // ---- pass C: replay chunk with correct start state, emit partial y ----
  for (int i4 = 0; i4 < 16; i4++) {
    float4 uv = *(float4*)&ubuf[lane][i4 * 4];
    float yv[4];
#pragma unroll
    for (int e = 0; e < 4; e++) {
      float u_ = (e == 0) ? uv.x : (e == 1) ? uv.y : (e == 2) ? uv.z : uv.w;
      float yacc = 0.f;
#pragma unroll
      for (int nn = 0; nn < 16; nn++) {
        float t = fmaf(-wi[nn], Si[nn], u_);
        float sr = fmaf(wr[nn], Sr[nn], t);
        float si = fmaf(wi[nn], Sr[nn], wr[nn] * Si[nn]);
        Sr[nn] = sr; Si[nn] = si;
        yacc = fmaf(cr[nn], sr, fmaf(-ci[nn], si, yacc));
      }
      yv[e] = yacc;
    }
    float4 st; st.x = yv[0]; st.y = yv[1]; st.z = yv[2]; st.w = yv[3];
    *(float4*)&ybuf[wv][lane][i4 * 4] = st;
  }
  __syncthreads();

  // ---- combine partials, +D*u, gelu, bf16 store ----
  float Dh = D[h];
#pragma unroll
  for (int it = 0; it < 8; it++) {
    int i4 = it * 128 + tid;
    int row = i4 >> 4, c4 = (i4 & 15) * 4;
    float4 p0 = *(float4*)&ybuf[0][row][c4];
    float4 p1 = *(float4*)&ybuf[1][row][c4];
    float4 uu = *(float4*)&ubuf[row][c4];
    ushort4 st;
    {
      float y = p0.x + p1.x + Dh * uu.x;
      st.x = f2bf(0.5f * y * (1.f + erff(y * 0.70710678118654752f)));
      y = p0.y + p1.y + Dh * uu.y;
      st.y = f2bf(0.5f * y * (1.f + erff(y * 0.70710678118654752f)));
      y = p0.z + p1.z + Dh * uu.z;
      st.z = f2bf(0.5f * y * (1.f + erff(y * 0.70710678118654752f)));
      y = p0.w + p1.w + Dh * uu.w;
      st.w = f2bf(0.5f * y * (1.f + erff(y * 0.70710678118654752f)));
    }
    *(ushort4*)(yws + (size_t)bh * L_DIM + i4 * 4) = st;
  }
}

// ---------------------------------------------------------------------------
__global__ __launch_bounds__(256) void transpose_kernel(
    const unsigned short* __restrict__ yws, unsigned short* __restrict__ yT) {
  __shared__ unsigned short tile[64][68];
  int bid = blockIdx.x;
  int lb = bid & 63, hb = (bid >> 6) & 15, b = bid >> 10;
  int h0 = hb * 64, l0 = lb * 64, tid = threadIdx.x;
#pragma unroll
  for (int it = 0; it < 4; it++) {
    int i4 = it * 256 + tid;  // 0..1023
    int hr = i4 >> 4, c4 = (i4 & 15) * 4;
    ushort4 v = *(const ushort4*)(yws + ((size_t)(b * H_DIM + h0 + hr)) * L_DIM + l0 + c4);
    *(ushort4*)&tile[hr][c4] = v;
  }
  __syncthreads();
#pragma unroll
  for (int it = 0; it < 4; it++) {
    int i4 = it * 256 + tid;
    int lr = i4 >> 4, hc = (i4 & 15) * 4;
    ushort4 o;
    o.x = tile[hc + 0][lr]; o.y = tile[hc + 1][lr];
    o.z = tile[hc + 2][lr]; o.w = tile[hc + 3][lr];
    *(ushort4*)(yT + ((size_t)(b * L_DIM + l0 + lr)) * H_DIM + h0 + hc) = o;
  }
}

// ---------------------------------------------------------------------------
// GEMM: z = W(2048x1024) @ yT^T, fused GLU. Tile: 128 gathered M-rows
// (64 'a' rows m0.., 64 'g' rows 1024+m0..) x 128 N-cols, BK=64.
// 4 waves (2x2); wave owns frag-rows {2wm,2wm+1,2wm+4,2wm+5} so (a,g) pairs
// are register-local in the epilogue.
__global__ __launch_bounds__(256) void gemm_kernel(
    const unsigned short* __restrict__ Wbf, const unsigned short* __restrict__ yT,
    const float* __restrict__ b_out, float* __restrict__ out) {
  __shared__ char smem[2][2][16384] __attribute__((aligned(16)));
  int bid = blockIdx.x;
  int swz = (bid & 7) * 512 + (bid >> 3);  // XCD-contiguous nb ranges
  int mb = swz & 15, nb = swz >> 4;
  int m0 = mb * 64;
  int n0 = nb * 128;
  int b = n0 >> 12, l0 = n0 & (L_DIM - 1);
  int tid = threadIdx.x, lane = tid & 63, wid = tid >> 6;
  int wm = wid >> 1, wn = wid & 1;

  const char* Abase = (const char*)Wbf;                                   // row stride 2048B
  const char* Bbase = (const char*)yT + ((size_t)b * L_DIM + l0) * 2048;  // row stride 2048B
  int rsub = lane >> 3;
  int csw = ((lane & 7) ^ rsub) * 16;  // pre-swizzled source chunk

  f32x4 acc[4][4];
#pragma unroll
  for (int i = 0; i < 4; i++)
#pragma unroll
    for (int j = 0; j < 4; j++) acc[i][j] = (f32x4)0.f;

  // fragment row byte offsets (swizzle applied at read via kb)
  int rowA[4], rowB[4];
#pragma unroll
  for (int ar = 0; ar < 4; ar++) {
    int f = 2 * wm + (ar & 1) + (ar >> 1) * 4;
    rowA[ar] = (f * 16 + (lane & 15)) * 128;
  }
#pragma unroll
  for (int bn = 0; bn < 4; bn++) {
    rowB[bn] = ((wn * 4 + bn) * 16 + (lane & 15)) * 128;
  }
  int koff = (lane >> 4) * 16;
  int sw = (lane & 7) << 4;

  // staging: wave 0 -> A rows m0.. , wave 1 -> A rows 1024+m0.. , waves 2,3 -> B
  const char* gsrc;
  char* ldst;
  if (wid == 0) {
    gsrc = Abase + (size_t)(m0 + rsub) * 2048 + csw;
    ldst = (char*)smem + 0 * 16384 + lane * 16;            // A instrs 0..7
  } else if (wid == 1) {
    gsrc = Abase + (size_t)(1024 + m0 + rsub) * 2048 + csw;
    ldst = (char*)smem + 0 * 16384 + 8192 + lane * 16;     // A instrs 8..15
  } else if (wid == 2) {
    gsrc = Bbase + (size_t)rsub * 2048 + csw;
    ldst = (char*)smem + 1 * 16384 + lane * 16;            // B instrs 0..7
  } else {
    gsrc = Bbase + (size_t)(64 + rsub) * 2048 + csw;
    ldst = (char*)smem + 1 * 16384 + 8192 + lane * 16;     // B instrs 8..15
  }

  // prologue stage ks=0 into buf 0
#pragma unroll
  for (int i = 0; i < 8; i++) GLOAD16(gsrc + (size_t)i * 8 * 2048, ldst + i * 1024);

  for (int ks = 0; ks < 16; ks++) {
    __syncthreads();  // drains vmcnt -> current buffer ready; guards overwrite
    int cur = ks & 1;
    if (ks < 15) {
      const char* g = gsrc + (size_t)(ks + 1) * 128;
      char* l = ldst + (cur ^ 1) * 32768;
#pragma unroll
      for (int i = 0; i < 8; i++) GLOAD16(g + (size_t)i * 8 * 2048, l + i * 1024);
    }
    const char* LA = smem[cur][0];
    const char* LB = smem[cur][1];
#pragma unroll
    for (int ksl = 0; ksl < 2; ksl++) {
      int kb = (ksl * 64 + koff) ^ sw;
      short8v av[4], bv[4];
#pragma unroll
      for (int ar = 0; ar < 4; ar++) av[ar] = *(const short8v*)(LA + rowA[ar] + kb);
#pragma unroll
      for (int bn = 0; bn < 4; bn++) bv[bn] = *(const short8v*)(LB + rowB[bn] + kb);
#pragma unroll
      for (int ar = 0; ar < 4; ar++)
#pragma unroll
        for (int bn = 0; bn < 4; bn++)
          acc[ar][bn] = __builtin_amdgcn_mfma_f32_16x16x32_bf16(av[ar], bv[bn], acc[ar][bn], 0, 0, 0);
    }
  }

  // ---- epilogue: a*sigmoid(g), register-local pairs (ar, ar+2) ----
#pragma unroll
  for (int q = 0; q < 2; q++) {
    int obase = m0 + (2 * wm + q) * 16 + (lane >> 4) * 4;
    float4 ba = *(const float4*)&b_out[obase];
    float4 bg = *(const float4*)&b_out[1024 + obase];
    float bav[4] = {ba.x, ba.y, ba.z, ba.w};
    float bgv[4] = {bg.x, bg.y, bg.z, bg.w};
#pragma unroll
    for (int bn = 0; bn < 4; bn++) {
      int col = l0 + (wn * 4 + bn) * 16 + (lane & 15);
      float* op = out + ((size_t)b * H_DIM + obase) * L_DIM + col;
#pragma unroll
      for (int r = 0; r < 4; r++) {
        float a_ = acc[q][bn][r] + bav[r];
        float g_ = acc[q + 2][bn][r] + bgv[r];
        op[(size_t)r * L_DIM] = a_ * (1.f / (1.f + expf(-g_)));
      }
    }
  }
}

// ---------------------------------------------------------------------------
extern "C" void kernel_launch(void* const* d_in, const int* in_sizes, int n_in,
                              void* d_out, int out_size, void* d_ws, size_t ws_size,
                              hipStream_t stream) {
  const float* u          = (const float*)d_in[0];
  const float* log_dt     = (const float*)d_in[1];
  const float* C_real     = (const float*)d_in[2];
  const float* log_A_real = (const float*)d_in[3];
  const float* A_imag     = (const float*)d_in[4];
  const float* D          = (const float*)d_in[5];
  const float* W_out      = (const float*)d_in[6];
  const float* b_out      = (const float*)d_in[7];
  float* out = (float*)d_out;

  char* ws = (char*)d_ws;
  float2* wtab = (float2*)(ws + 0);                      // 256 KB
  float2* ctab = (float2*)(ws + (1 << 18));              // 256 KB
  float2* mtab = (float2*)(ws + (1 << 19));              // 1.5 MB
  unsigned short* Wbf = (unsigned short*)(ws + (2 << 20));   // 4 MB
  unsigned short* yws = (unsigned short*)(ws + (8ull << 20));   // 64 MB
  unsigned short* yT  = (unsigned short*)(ws + (76ull << 20));  // 64 MB

  prep_tables<<<128, 256, 0, stream>>>(log_dt, C_real, log_A_real, A_imag, wtab, ctab, mtab);
  prep_w<<<2048, 256, 0, stream>>>(W_out, Wbf);
  scan_kernel<<<B_DIM * H_DIM, 128, 0, stream>>>(u, wtab, ctab, mtab, D, yws);
  transpose_kernel<<<8192, 256, 0, stream>>>(yws, yT);
  gemm_kernel<<<4096, 256, 0, stream>>>(Wbf, yT, b_out, out);
}

// Round 2
// 711.207 us; speedup vs baseline: 1.0528x; 1.0528x over previous
//
#include <hip/hip_runtime.h>
#include <hip/hip_bf16.h>
#include <math.h>

// ---------------------------------------------------------------------------
// S4D SSM fused pipeline:
//  prep_tables: f64-accurate per-(h,n) constants: w=exp(dtA), c=2*C*(w-1)/A,
//               mtab[s]=w^(64*2^s) for the cross-lane scan
//  prep_w:      W_out f32 -> bf16
//  scan:        chunked linear-recurrence scan -> y = gelu(conv(k,u)+D*u) (bf16)
//               v2: 23.5 KB LDS (was 52 KB) -> 6 blocks/CU; phase-pipelined
//               cross-wave combine through a 3 KB 2-deep buffer; swizzled ubuf.
//  transpose:   y (b,h,l) -> yT (b,l,h)  so GEMM B-operand is k-contiguous
//  gemm:        z = W*y + b, GLU fused epilogue out = a*sigmoid(g)
// ---------------------------------------------------------------------------

#define H_DIM 1024
#define N2_DIM 32
#define B_DIM 8
#define L_DIM 4096

typedef __attribute__((ext_vector_type(8))) short short8v;
typedef __attribute__((ext_vector_type(4))) float f32x4;

#define GLOAD16(g, l) __builtin_amdgcn_global_load_lds( \
    (const __attribute__((address_space(1))) unsigned int*)(g), \
    (__attribute__((address_space(3))) unsigned int*)(l), 16, 0, 0)

__device__ __forceinline__ unsigned short f2bf(float x) {
  unsigned int v = __float_as_uint(x);
  unsigned int r = (v + 0x7fff + ((v >> 16) & 1)) >> 16;
  return (unsigned short)r;
}

__device__ __forceinline__ float gelu_exact(float y) {
  return 0.5f * y * (1.f + erff(y * 0.70710678118654752f));
}

// ---------------------------------------------------------------------------
__global__ __launch_bounds__(256) void prep_tables(
    const float* __restrict__ log_dt, const float* __restrict__ C_real,
    const float* __restrict__ log_A_real, const float* __restrict__ A_imag,
    float2* __restrict__ wtab, float2* __restrict__ ctab, float2* __restrict__ mtab) {
  int idx = blockIdx.x * 256 + threadIdx.x;  // 32768 = H*N2
  int h = idx >> 5;
  double dt = exp((double)log_dt[h]);
  double Ar = -exp((double)log_A_real[idx]);
  double Ai = (double)A_imag[idx];
  double xr = dt * Ar, xi = dt * Ai;               // dtA
  double er = exp(xr);
  double wr = er * cos(xi), wi = er * sin(xi);     // w = exp(dtA)
  wtab[idx] = make_float2((float)wr, (float)wi);
  double crr = (double)C_real[2 * idx], cii = (double)C_real[2 * idx + 1];
  double nr = wr - 1.0, ni = wi;
  double den = Ar * Ar + Ai * Ai;
  double qr = (nr * Ar + ni * Ai) / den, qi = (ni * Ar - nr * Ai) / den;  // (w-1)/A
  ctab[idx] = make_float2((float)(2.0 * (crr * qr - cii * qi)),
                          (float)(2.0 * (crr * qi + cii * qr)));
#pragma unroll
  for (int s = 0; s < 6; s++) {
    double p = (double)(64 << s);
    double pr = exp(p * xr);
    mtab[idx * 6 + s] = make_float2((float)(pr * cos(p * xi)), (float)(pr * sin(p * xi)));
  }
}

// ---------------------------------------------------------------------------
__global__ __launch_bounds__(256) void prep_w(const float* __restrict__ W,
                                              unsigned short* __restrict__ Wbf) {
  int i = blockIdx.x * 256 + threadIdx.x;  // per float4, 2048*1024/4 = 524288
  float4 v = ((const float4*)W)[i];
  ushort4 o;
  o.x = f2bf(v.x); o.y = f2bf(v.y); o.z = f2bf(v.z); o.w = f2bf(v.w);
  ((ushort4*)Wbf)[i] = o;
}

// ---------------------------------------------------------------------------
// scan v2: one block (128 thr = 2 waves) per (b,h). Wave wv owns states
// n in [wv*16, wv*16+16). Lane j owns timesteps [j*64,(j+1)*64).
// LDS: ubuf 17.4 KB (col-swizzled, conflict-free) + ybuf 3 KB (2-deep
// phase-pipelined cross-wave exchange) = 23.5 KB -> 6 blocks/CU (3 waves/SIMD).
__global__ __launch_bounds__(128, 3) void scan_kernel(
    const float* __restrict__ u, const float2* __restrict__ wtab,
    const float2* __restrict__ ctab, const float2* __restrict__ mtab,
    const float* __restrict__ D, unsigned short* __restrict__ yws) {
  __shared__ float ubuf[64][68];      // row = 64-step chunk, col-swizzled float4 slots
  __shared__ float ybuf[2][64][12];   // [phase&1][lane][2 float4 + pad]
  int bh = blockIdx.x;
  int h = bh & (H_DIM - 1);
  int tid = threadIdx.x, lane = tid & 63, wv = tid >> 6;

  // coalesced stage u -> ubuf (swizzle: slot c of row r stored at c ^ ((r>>3)&7))
  const float4* urow = (const float4*)(u + (size_t)bh * L_DIM);
#pragma unroll
  for (int it = 0; it < 8; it++) {
    int i4 = it * 128 + tid;  // 0..1023
    float4 v = urow[i4];
    int r = i4 >> 4, c = i4 & 15;
    *(float4*)&ubuf[r][(c ^ ((r >> 3) & 7)) * 4] = v;
  }

  float wr[16], wi[16], cr[16], ci[16];
  int nbase = h * N2_DIM + wv * 16;
#pragma unroll
  for (int nn = 0; nn < 16; nn++) {
    float2 a = wtab[nbase + nn]; wr[nn] = a.x; wi[nn] = a.y;
    float2 c = ctab[nbase + nn]; cr[nn] = c.x; ci[nn] = c.y;
  }
  __syncthreads();

  int lsw = (lane >> 3) & 7;  // read-side swizzle key (row == lane)

  // ---- pass A: chunk-local states from zero ----
  float Sr[16], Si[16];
#pragma unroll
  for (int nn = 0; nn < 16; nn++) { Sr[nn] = 0.f; Si[nn] = 0.f; }
  for (int i4 = 0; i4 < 16; i4++) {
    float4 uv = *(float4*)&ubuf[lane][(i4 ^ lsw) * 4];
#pragma unroll
    for (int e = 0; e < 4; e++) {
      float u_ = (e == 0) ? uv.x : (e == 1) ? uv.y : (e == 2) ? uv.z : uv.w;
#pragma unroll
      for (int nn = 0; nn < 16; nn++) {
        float t = fmaf(-wi[nn], Si[nn], u_);
        float sr = fmaf(wr[nn], Sr[nn], t);
        float si = fmaf(wi[nn], Sr[nn], wr[nn] * Si[nn]);
        Sr[nn] = sr; Si[nn] = si;
      }
    }
  }

  // ---- cross-lane inclusive scan (Hillis-Steele, decay w^64 per chunk) ----
#pragma unroll
  for (int s = 0; s < 6; s++) {
    int d = 1 << s;
#pragma unroll
    for (int nn = 0; nn < 16; nn++) {
      float2 m = mtab[(nbase + nn) * 6 + s];  // w^(64*2^s), f64-accurate
      float rr = __shfl_up(Sr[nn], d, 64);
      float ri = __shfl_up(Si[nn], d, 64);
      rr = (lane >= d) ? rr : 0.f;
      ri = (lane >= d) ? ri : 0.f;
      Sr[nn] = fmaf(m.x, rr, fmaf(-m.y, ri, Sr[nn]));
      Si[nn] = fmaf(m.x, ri, fmaf(m.y, rr, Si[nn]));
    }
  }
  // exclusive shift: state at chunk start
#pragma unroll
  for (int nn = 0; nn < 16; nn++) {
    float er = __shfl_up(Sr[nn], 1, 64);
    float ei = __shfl_up(Si[nn], 1, 64);
    Sr[nn] = lane ? er : 0.f;
    Si[nn] = lane ? ei : 0.f;
  }

  // ---- pass C: replay in 8 phases of 8 steps; pipelined cross-wave combine.
  // w0 writes partial into ybuf[p&1]; after the barrier w1 (partial in regs)
  // combines phase p while w0 computes phase p+1 into the other half.
  float Dh = D[h];
  for (int p = 0; p < 8; p++) {
    float yv[2][4];
    float4 uq[2];
#pragma unroll
    for (int q = 0; q < 2; q++) {
      int i4 = 2 * p + q;
      float4 uv = *(float4*)&ubuf[lane][(i4 ^ lsw) * 4];
      uq[q] = uv;
#pragma unroll
      for (int e = 0; e < 4; e++) {
        float u_ = (e == 0) ? uv.x : (e == 1) ? uv.y : (e == 2) ? uv.z : uv.w;
        float yacc = 0.f;
#pragma unroll
        for (int nn = 0; nn < 16; nn++) {
          float t = fmaf(-wi[nn], Si[nn], u_);
          float sr = fmaf(wr[nn], Sr[nn], t);
          float si = fmaf(wi[nn], Sr[nn], wr[nn] * Si[nn]);
          Sr[nn] = sr; Si[nn] = si;
          yacc = fmaf(cr[nn], sr, fmaf(-ci[nn], si, yacc));
        }
        yv[q][e] = yacc;
      }
    }
    if (wv == 0) {
      float4 s0; s0.x = yv[0][0]; s0.y = yv[0][1]; s0.z = yv[0][2]; s0.w = yv[0][3];
      float4 s1; s1.x = yv[1][0]; s1.y = yv[1][1]; s1.z = yv[1][2]; s1.w = yv[1][3];
      *(float4*)&ybuf[p & 1][lane][0] = s0;
      *(float4*)&ybuf[p & 1][lane][4] = s1;
    }
    __syncthreads();
    if (wv == 1) {
#pragma unroll
      for (int q = 0; q < 2; q++) {
        float4 p0 = *(float4*)&ybuf[p & 1][lane][q * 4];
        float4 uu = uq[q];
        ushort4 st;
        float y;
        y = p0.x + yv[q][0] + Dh * uu.x; st.x = f2bf(gelu_exact(y));
        y = p0.y + yv[q][1] + Dh * uu.y; st.y = f2bf(gelu_exact(y));
        y = p0.z + yv[q][2] + Dh * uu.z; st.z = f2bf(gelu_exact(y));
        y = p0.w + yv[q][3] + Dh * uu.w; st.w = f2bf(gelu_exact(y));
        *(ushort4*)(yws + (size_t)bh * L_DIM + lane * 64 + (2 * p + q) * 4) = st;
      }
    }
    // hazard note: w0's next overwrite of half (p&1) happens at phase p+2,
    // which is after barrier p+1; w1's read completes before barrier p+1. safe.
  }
}

// ---------------------------------------------------------------------------
__global__ __launch_bounds__(256) void transpose_kernel(
    const unsigned short* __restrict__ yws, unsigned short* __restrict__ yT) {
  __shared__ unsigned short tile[64][68];
  int bid = blockIdx.x;
  int lb = bid & 63, hb = (bid >> 6) & 15, b = bid >> 10;
  int h0 = hb * 64, l0 = lb * 64, tid = threadIdx.x;
#pragma unroll
  for (int it = 0; it < 4; it++) {
    int i4 = it * 256 + tid;  // 0..1023
    int hr = i4 >> 4, c4 = (i4 & 15) * 4;
    ushort4 v = *(const ushort4*)(yws + ((size_t)(b * H_DIM + h0 + hr)) * L_DIM + l0 + c4);
    *(ushort4*)&tile[hr][c4] = v;
  }
  __syncthreads();
#pragma unroll
  for (int it = 0; it < 4; it++) {
    int i4 = it * 256 + tid;
    int lr = i4 >> 4, hc = (i4 & 15) * 4;
    ushort4 o;
    o.x = tile[hc + 0][lr]; o.y = tile[hc + 1][lr];
    o.z = tile[hc + 2][lr]; o.w = tile[hc + 3][lr];
    *(ushort4*)(yT + ((size_t)(b * L_DIM + l0 + lr)) * H_DIM + h0 + hc) = o;
  }
}

// ---------------------------------------------------------------------------
// GEMM: z = W(2048x1024) @ yT^T, fused GLU. Tile: 128 gathered M-rows
// (64 'a' rows m0.., 64 'g' rows 1024+m0..) x 128 N-cols, BK=64.
// 4 waves (2x2); wave owns frag-rows {2wm,2wm+1,2wm+4,2wm+5} so (a,g) pairs
// are register-local in the epilogue.
__global__ __launch_bounds__(256) void gemm_kernel(
    const unsigned short* __restrict__ Wbf, const unsigned short* __restrict__ yT,
    const float* __restrict__ b_out, float* __restrict__ out) {
  __shared__ char smem[2][2][16384] __attribute__((aligned(16)));
  int bid = blockIdx.x;
  int swz = (bid & 7) * 512 + (bid >> 3);  // XCD-contiguous nb ranges
  int mb = swz & 15, nb = swz >> 4;
  int m0 = mb * 64;
  int n0 = nb * 128;
  int b = n0 >> 12, l0 = n0 & (L_DIM - 1);
  int tid = threadIdx.x, lane = tid & 63, wid = tid >> 6;
  int wm = wid >> 1, wn = wid & 1;

  const char* Abase = (const char*)Wbf;                                   // row stride 2048B
  const char* Bbase = (const char*)yT + ((size_t)b * L_DIM + l0) * 2048;  // row stride 2048B
  int rsub = lane >> 3;
  int csw = ((lane & 7) ^ rsub) * 16;  // pre-swizzled source chunk

  f32x4 acc[4][4];
#pragma unroll
  for (int i = 0; i < 4; i++)
#pragma unroll
    for (int j = 0; j < 4; j++) acc[i][j] = (f32x4)0.f;

  // fragment row byte offsets (swizzle applied at read via kb)
  int rowA[4], rowB[4];
#pragma unroll
  for (int ar = 0; ar < 4; ar++) {
    int f = 2 * wm + (ar & 1) + (ar >> 1) * 4;
    rowA[ar] = (f * 16 + (lane & 15)) * 128;
  }
#pragma unroll
  for (int bn = 0; bn < 4; bn++) {
    rowB[bn] = ((wn * 4 + bn) * 16 + (lane & 15)) * 128;
  }
  int koff = (lane >> 4) * 16;
  int sw = (lane & 7) << 4;

  // staging: wave 0 -> A rows m0.. , wave 1 -> A rows 1024+m0.. , waves 2,3 -> B
  const char* gsrc;
  char* ldst;
  if (wid == 0) {
    gsrc = Abase + (size_t)(m0 + rsub) * 2048 + csw;
    ldst = (char*)smem + 0 * 16384 + lane * 16;            // A instrs 0..7
  } else if (wid == 1) {
    gsrc = Abase + (size_t)(1024 + m0 + rsub) * 2048 + csw;
    ldst = (char*)smem + 0 * 16384 + 8192 + lane * 16;     // A instrs 8..15
  } else if (wid == 2) {
    gsrc = Bbase + (size_t)rsub * 2048 + csw;
    ldst = (char*)smem + 1 * 16384 + lane * 16;            // B instrs 0..7
  } else {
    gsrc = Bbase + (size_t)(64 + rsub) * 2048 + csw;
    ldst = (char*)smem + 1 * 16384 + 8192 + lane * 16;     // B instrs 8..15
  }

  // prologue stage ks=0 into buf 0
#pragma unroll
  for (int i = 0; i < 8; i++) GLOAD16(gsrc + (size_t)i * 8 * 2048, ldst + i * 1024);

  for (int ks = 0; ks < 16; ks++) {
    __syncthreads();  // drains vmcnt -> current buffer ready; guards overwrite
    int cur = ks & 1;
    if (ks < 15) {
      const char* g = gsrc + (size_t)(ks + 1) * 128;
      char* l = ldst + (cur ^ 1) * 32768;
#pragma unroll
      for (int i = 0; i < 8; i++) GLOAD16(g + (size_t)i * 8 * 2048, l + i * 1024);
    }
    const char* LA = smem[cur][0];
    const char* LB = smem[cur][1];
#pragma unroll
    for (int ksl = 0; ksl < 2; ksl++) {
      int kb = (ksl * 64 + koff) ^ sw;
      short8v av[4], bv[4];
#pragma unroll
      for (int ar = 0; ar < 4; ar++) av[ar] = *(const short8v*)(LA + rowA[ar] + kb);
#pragma unroll
      for (int bn = 0; bn < 4; bn++) bv[bn] = *(const short8v*)(LB + rowB[bn] + kb);
#pragma unroll
      for (int ar = 0; ar < 4; ar++)
#pragma unroll
        for (int bn = 0; bn < 4; bn++)
          acc[ar][bn] = __builtin_amdgcn_mfma_f32_16x16x32_bf16(av[ar], bv[bn], acc[ar][bn], 0, 0, 0);
    }
  }

  // ---- epilogue: a*sigmoid(g), register-local pairs (ar, ar+2) ----
#pragma unroll
  for (int q = 0; q < 2; q++) {
    int obase = m0 + (2 * wm + q) * 16 + (lane >> 4) * 4;
    float4 ba = *(const float4*)&b_out[obase];
    float4 bg = *(const float4*)&b_out[1024 + obase];
    float bav[4] = {ba.x, ba.y, ba.z, ba.w};
    float bgv[4] = {bg.x, bg.y, bg.z, bg.w};
#pragma unroll
    for (int bn = 0; bn < 4; bn++) {
      int col = l0 + (wn * 4 + bn) * 16 + (lane & 15);
      float* op = out + ((size_t)b * H_DIM + obase) * L_DIM + col;
#pragma unroll
      for (int r = 0; r < 4; r++) {
        float a_ = acc[q][bn][r] + bav[r];
        float g_ = acc[q + 2][bn][r] + bgv[r];
        op[(size_t)r * L_DIM] = a_ * (1.f / (1.f + expf(-g_)));
      }
    }
  }
}

// ---------------------------------------------------------------------------
extern "C" void kernel_launch(void* const* d_in, const int* in_sizes, int n_in,
                              void* d_out, int out_size, void* d_ws, size_t ws_size,
                              hipStream_t stream) {
  const float* u          = (const float*)d_in[0];
  const float* log_dt     = (const float*)d_in[1];
  const float* C_real     = (const float*)d_in[2];
  const float* log_A_real = (const float*)d_in[3];
  const float* A_imag     = (const float*)d_in[4];
  const float* D          = (const float*)d_in[5];
  const float* W_out      = (const float*)d_in[6];
  const float* b_out      = (const float*)d_in[7];
  float* out = (float*)d_out;

  char* ws = (char*)d_ws;
  float2* wtab = (float2*)(ws + 0);                      // 256 KB
  float2* ctab = (float2*)(ws + (1 << 18));              // 256 KB
  float2* mtab = (float2*)(ws + (1 << 19));              // 1.5 MB
  unsigned short* Wbf = (unsigned short*)(ws + (2 << 20));   // 4 MB
  unsigned short* yws = (unsigned short*)(ws + (8ull << 20));   // 64 MB
  unsigned short* yT  = (unsigned short*)(ws + (76ull << 20));  // 64 MB

  prep_tables<<<128, 256, 0, stream>>>(log_dt, C_real, log_A_real, A_imag, wtab, ctab, mtab);
  prep_w<<<2048, 256, 0, stream>>>(W_out, Wbf);
  scan_kernel<<<B_DIM * H_DIM, 128, 0, stream>>>(u, wtab, ctab, mtab, D, yws);
  transpose_kernel<<<8192, 256, 0, stream>>>(yws, yT);
  gemm_kernel<<<4096, 256, 0, stream>>>(Wbf, yT, b_out, out);
}

// Round 3
// 678.813 us; speedup vs baseline: 1.1030x; 1.0477x over previous
//
#include <hip/hip_runtime.h>
#include <hip/hip_bf16.h>
#include <math.h>

// ---------------------------------------------------------------------------
// S4D SSM fused pipeline:
//  prep_tables: f64-accurate per-(h,n) constants: w=exp(dtA), c=2*C*(w-1)/A,
//               mtab[s]=w^(64*2^s) for the cross-lane scan
//  prep_w:      W_out f32 -> bf16
//  scan:        chunked linear-recurrence scan -> y = gelu(conv(k,u)+D*u) (bf16)
//               v3: 23.5 KB LDS, phase-pipelined cross-wave combine, and NO
//               min-waves launch-bounds arg (v2's ",3" capped VGPR at 84 and
//               spilled the 96-reg state arrays -> +270 MB scratch traffic).
//               VGPR ~144 -> 3 waves/EU naturally; LDS allows the 6 blocks/CU.
//  transpose:   y (b,h,l) -> yT (b,l,h)  so GEMM B-operand is k-contiguous
//  gemm:        z = W*y + b, GLU fused epilogue out = a*sigmoid(g)
// ---------------------------------------------------------------------------

#define H_DIM 1024
#define N2_DIM 32
#define B_DIM 8
#define L_DIM 4096

typedef __attribute__((ext_vector_type(8))) short short8v;
typedef __attribute__((ext_vector_type(4))) float f32x4;

#define GLOAD16(g, l) __builtin_amdgcn_global_load_lds( \
    (const __attribute__((address_space(1))) unsigned int*)(g), \
    (__attribute__((address_space(3))) unsigned int*)(l), 16, 0, 0)

__device__ __forceinline__ unsigned short f2bf(float x) {
  unsigned int v = __float_as_uint(x);
  unsigned int r = (v + 0x7fff + ((v >> 16) & 1)) >> 16;
  return (unsigned short)r;
}

__device__ __forceinline__ float gelu_exact(float y) {
  return 0.5f * y * (1.f + erff(y * 0.70710678118654752f));
}

// ---------------------------------------------------------------------------
__global__ __launch_bounds__(256) void prep_tables(
    const float* __restrict__ log_dt, const float* __restrict__ C_real,
    const float* __restrict__ log_A_real, const float* __restrict__ A_imag,
    float2* __restrict__ wtab, float2* __restrict__ ctab, float2* __restrict__ mtab) {
  int idx = blockIdx.x * 256 + threadIdx.x;  // 32768 = H*N2
  int h = idx >> 5;
  double dt = exp((double)log_dt[h]);
  double Ar = -exp((double)log_A_real[idx]);
  double Ai = (double)A_imag[idx];
  double xr = dt * Ar, xi = dt * Ai;               // dtA
  double er = exp(xr);
  double wr = er * cos(xi), wi = er * sin(xi);     // w = exp(dtA)
  wtab[idx] = make_float2((float)wr, (float)wi);
  double crr = (double)C_real[2 * idx], cii = (double)C_real[2 * idx + 1];
  double nr = wr - 1.0, ni = wi;
  double den = Ar * Ar + Ai * Ai;
  double qr = (nr * Ar + ni * Ai) / den, qi = (ni * Ar - nr * Ai) / den;  // (w-1)/A
  ctab[idx] = make_float2((float)(2.0 * (crr * qr - cii * qi)),
                          (float)(2.0 * (crr * qi + cii * qr)));
#pragma unroll
  for (int s = 0; s < 6; s++) {
    double p = (double)(64 << s);
    double pr = exp(p * xr);
    mtab[idx * 6 + s] = make_float2((float)(pr * cos(p * xi)), (float)(pr * sin(p * xi)));
  }
}

// ---------------------------------------------------------------------------
__global__ __launch_bounds__(256) void prep_w(const float* __restrict__ W,
                                              unsigned short* __restrict__ Wbf) {
  int i = blockIdx.x * 256 + threadIdx.x;  // per float4, 2048*1024/4 = 524288
  float4 v = ((const float4*)W)[i];
  ushort4 o;
  o.x = f2bf(v.x); o.y = f2bf(v.y); o.z = f2bf(v.z); o.w = f2bf(v.w);
  ((ushort4*)Wbf)[i] = o;
}

// ---------------------------------------------------------------------------
// scan v3: one block (128 thr = 2 waves) per (b,h). Wave wv owns states
// n in [wv*16, wv*16+16). Lane j owns timesteps [j*64,(j+1)*64).
// LDS: ubuf 17.4 KB (col-swizzled) + ybuf 3 KB (2-deep phase-pipelined
// cross-wave exchange) = 23.5 KB -> 6 blocks/CU.
// NOTE: no min-waves arg in launch_bounds — with one (",3") the allocator
// capped VGPR at 84 < the ~96-reg live state set and spilled to scratch
// (+270 MB HBM traffic, round-2 profile). 144 VGPR -> 3 waves/EU naturally.
__global__ __launch_bounds__(128) void scan_kernel(
    const float* __restrict__ u, const float2* __restrict__ wtab,
    const float2* __restrict__ ctab, const float2* __restrict__ mtab,
    const float* __restrict__ D, unsigned short* __restrict__ yws) {
  __shared__ float ubuf[64][68];      // row = 64-step chunk, col-swizzled float4 slots
  __shared__ float ybuf[2][64][12];   // [phase&1][lane][2 float4 + pad]
  int bh = blockIdx.x;
  int h = bh & (H_DIM - 1);
  int tid = threadIdx.x, lane = tid & 63, wv = tid >> 6;

  // coalesced stage u -> ubuf (swizzle: slot c of row r stored at c ^ ((r>>3)&7))
  const float4* urow = (const float4*)(u + (size_t)bh * L_DIM);
#pragma unroll
  for (int it = 0; it < 8; it++) {
    int i4 = it * 128 + tid;  // 0..1023
    float4 v = urow[i4];
    int r = i4 >> 4, c = i4 & 15;
    *(float4*)&ubuf[r][(c ^ ((r >> 3) & 7)) * 4] = v;
  }

  float wr[16], wi[16], cr[16], ci[16];
  int nbase = h * N2_DIM + wv * 16;
#pragma unroll
  for (int nn = 0; nn < 16; nn++) {
    float2 a = wtab[nbase + nn]; wr[nn] = a.x; wi[nn] = a.y;
    float2 c = ctab[nbase + nn]; cr[nn] = c.x; ci[nn] = c.y;
  }
  __syncthreads();

  int lsw = (lane >> 3) & 7;  // read-side swizzle key (row == lane)

  // ---- pass A: chunk-local states from zero ----
  float Sr[16], Si[16];
#pragma unroll
  for (int nn = 0; nn < 16; nn++) { Sr[nn] = 0.f; Si[nn] = 0.f; }
  for (int i4 = 0; i4 < 16; i4++) {
    float4 uv = *(float4*)&ubuf[lane][(i4 ^ lsw) * 4];
#pragma unroll
    for (int e = 0; e < 4; e++) {
      float u_ = (e == 0) ? uv.x : (e == 1) ? uv.y : (e == 2) ? uv.z : uv.w;
#pragma unroll
      for (int nn = 0; nn < 16; nn++) {
        float t = fmaf(-wi[nn], Si[nn], u_);
        float sr = fmaf(wr[nn], Sr[nn], t);
        float si = fmaf(wi[nn], Sr[nn], wr[nn] * Si[nn]);
        Sr[nn] = sr; Si[nn] = si;
      }
    }
  }

  // ---- cross-lane inclusive scan (Hillis-Steele, decay w^64 per chunk) ----
#pragma unroll
  for (int s = 0; s < 6; s++) {
    int d = 1 << s;
#pragma unroll
    for (int nn = 0; nn < 16; nn++) {
      float2 m = mtab[(nbase + nn) * 6 + s];  // w^(64*2^s), f64-accurate
      float rr = __shfl_up(Sr[nn], d, 64);
      float ri = __shfl_up(Si[nn], d, 64);
      rr = (lane >= d) ? rr : 0.f;
      ri = (lane >= d) ? ri : 0.f;
      Sr[nn] = fmaf(m.x, rr, fmaf(-m.y, ri, Sr[nn]));
      Si[nn] = fmaf(m.x, ri, fmaf(m.y, rr, Si[nn]));
    }
  }
  // exclusive shift: state at chunk start
#pragma unroll
  for (int nn = 0; nn < 16; nn++) {
    float er = __shfl_up(Sr[nn], 1, 64);
    float ei = __shfl_up(Si[nn], 1, 64);
    Sr[nn] = lane ? er : 0.f;
    Si[nn] = lane ? ei : 0.f;
  }

  // ---- pass C: replay in 8 phases of 8 steps; pipelined cross-wave combine.
  // w0 writes partial into ybuf[p&1]; after the barrier w1 (partial in regs)
  // combines phase p while w0 computes phase p+1 into the other half.
  float Dh = D[h];
  for (int p = 0; p < 8; p++) {
    float yv[2][4];
    float4 uq[2];
#pragma unroll
    for (int q = 0; q < 2; q++) {
      int i4 = 2 * p + q;
      float4 uv = *(float4*)&ubuf[lane][(i4 ^ lsw) * 4];
      uq[q] = uv;
#pragma unroll
      for (int e = 0; e < 4; e++) {
        float u_ = (e == 0) ? uv.x : (e == 1) ? uv.y : (e == 2) ? uv.z : uv.w;
        float yacc = 0.f;
#pragma unroll
        for (int nn = 0; nn < 16; nn++) {
          float t = fmaf(-wi[nn], Si[nn], u_);
          float sr = fmaf(wr[nn], Sr[nn], t);
          float si = fmaf(wi[nn], Sr[nn], wr[nn] * Si[nn]);
          Sr[nn] = sr; Si[nn] = si;
          yacc = fmaf(cr[nn], sr, fmaf(-ci[nn], si, yacc));
        }
        yv[q][e] = yacc;
      }
    }
    if (wv == 0) {
      float4 s0; s0.x = yv[0][0]; s0.y = yv[0][1]; s0.z = yv[0][2]; s0.w = yv[0][3];
      float4 s1; s1.x = yv[1][0]; s1.y = yv[1][1]; s1.z = yv[1][2]; s1.w = yv[1][3];
      *(float4*)&ybuf[p & 1][lane][0] = s0;
      *(float4*)&ybuf[p & 1][lane][4] = s1;
    }
    __syncthreads();
    if (wv == 1) {
#pragma unroll
      for (int q = 0; q < 2; q++) {
        float4 p0 = *(float4*)&ybuf[p & 1][lane][q * 4];
        float4 uu = uq[q];
        ushort4 st;
        float y;
        y = p0.x + yv[q][0] + Dh * uu.x; st.x = f2bf(gelu_exact(y));
        y = p0.y + yv[q][1] + Dh * uu.y; st.y = f2bf(gelu_exact(y));
        y = p0.z + yv[q][2] + Dh * uu.z; st.z = f2bf(gelu_exact(y));
        y = p0.w + yv[q][3] + Dh * uu.w; st.w = f2bf(gelu_exact(y));
        *(ushort4*)(yws + (size_t)bh * L_DIM + lane * 64 + (2 * p + q) * 4) = st;
      }
    }
    // hazard note: w0's next overwrite of half (p&1) happens at phase p+2,
    // which is after barrier p+1; w1's read completes before barrier p+1. safe.
  }
}

// ---------------------------------------------------------------------------
__global__ __launch_bounds__(256) void transpose_kernel(
    const unsigned short* __restrict__ yws, unsigned short* __restrict__ yT) {
  __shared__ unsigned short tile[64][68];
  int bid = blockIdx.x;
  int lb = bid & 63, hb = (bid >> 6) & 15, b = bid >> 10;
  int h0 = hb * 64, l0 = lb * 64, tid = threadIdx.x;
#pragma unroll
  for (int it = 0; it < 4; it++) {
    int i4 = it * 256 + tid;  // 0..1023
    int hr = i4 >> 4, c4 = (i4 & 15) * 4;
    ushort4 v = *(const ushort4*)(yws + ((size_t)(b * H_DIM + h0 + hr)) * L_DIM + l0 + c4);
    *(ushort4*)&tile[hr][c4] = v;
  }
  __syncthreads();
#pragma unroll
  for (int it = 0; it < 4; it++) {
    int i4 = it * 256 + tid;
    int lr = i4 >> 4, hc = (i4 & 15) * 4;
    ushort4 o;
    o.x = tile[hc + 0][lr]; o.y = tile[hc + 1][lr];
    o.z = tile[hc + 2][lr]; o.w = tile[hc + 3][lr];
    *(ushort4*)(yT + ((size_t)(b * L_DIM + l0 + lr)) * H_DIM + h0 + hc) = o;
  }
}

// ---------------------------------------------------------------------------
// GEMM: z = W(2048x1024) @ yT^T, fused GLU. Tile: 128 gathered M-rows
// (64 'a' rows m0.., 64 'g' rows 1024+m0..) x 128 N-cols, BK=64.
// 4 waves (2x2); wave owns frag-rows {2wm,2wm+1,2wm+4,2wm+5} so (a,g) pairs
// are register-local in the epilogue.
__global__ __launch_bounds__(256) void gemm_kernel(
    const unsigned short* __restrict__ Wbf, const unsigned short* __restrict__ yT,
    const float* __restrict__ b_out, float* __restrict__ out) {
  __shared__ char smem[2][2][16384] __attribute__((aligned(16)));
  int bid = blockIdx.x;
  int swz = (bid & 7) * 512 + (bid >> 3);  // XCD-contiguous nb ranges
  int mb = swz & 15, nb = swz >> 4;
  int m0 = mb * 64;
  int n0 = nb * 128;
  int b = n0 >> 12, l0 = n0 & (L_DIM - 1);
  int tid = threadIdx.x, lane = tid & 63, wid = tid >> 6;
  int wm = wid >> 1, wn = wid & 1;

  const char* Abase = (const char*)Wbf;                                   // row stride 2048B
  const char* Bbase = (const char*)yT + ((size_t)b * L_DIM + l0) * 2048;  // row stride 2048B
  int rsub = lane >> 3;
  int csw = ((lane & 7) ^ rsub) * 16;  // pre-swizzled source chunk

  f32x4 acc[4][4];
#pragma unroll
  for (int i = 0; i < 4; i++)
#pragma unroll
    for (int j = 0; j < 4; j++) acc[i][j] = (f32x4)0.f;

  // fragment row byte offsets (swizzle applied at read via kb)
  int rowA[4], rowB[4];
#pragma unroll
  for (int ar = 0; ar < 4; ar++) {
    int f = 2 * wm + (ar & 1) + (ar >> 1) * 4;
    rowA[ar] = (f * 16 + (lane & 15)) * 128;
  }
#pragma unroll
  for (int bn = 0; bn < 4; bn++) {
    rowB[bn] = ((wn * 4 + bn) * 16 + (lane & 15)) * 128;
  }
  int koff = (lane >> 4) * 16;
  int sw = (lane & 7) << 4;

  // staging: wave 0 -> A rows m0.. , wave 1 -> A rows 1024+m0.. , waves 2,3 -> B
  const char* gsrc;
  char* ldst;
  if (wid == 0) {
    gsrc = Abase + (size_t)(m0 + rsub) * 2048 + csw;
    ldst = (char*)smem + 0 * 16384 + lane * 16;            // A instrs 0..7
  } else if (wid == 1) {
    gsrc = Abase + (size_t)(1024 + m0 + rsub) * 2048 + csw;
    ldst = (char*)smem + 0 * 16384 + 8192 + lane * 16;     // A instrs 8..15
  } else if (wid == 2) {
    gsrc = Bbase + (size_t)rsub * 2048 + csw;
    ldst = (char*)smem + 1 * 16384 + lane * 16;            // B instrs 0..7
  } else {
    gsrc = Bbase + (size_t)(64 + rsub) * 2048 + csw;
    ldst = (char*)smem + 1 * 16384 + 8192 + lane * 16;     // B instrs 8..15
  }

  // prologue stage ks=0 into buf 0
#pragma unroll
  for (int i = 0; i < 8; i++) GLOAD16(gsrc + (size_t)i * 8 * 2048, ldst + i * 1024);

  for (int ks = 0; ks < 16; ks++) {
    __syncthreads();  // drains vmcnt -> current buffer ready; guards overwrite
    int cur = ks & 1;
    if (ks < 15) {
      const char* g = gsrc + (size_t)(ks + 1) * 128;
      char* l = ldst + (cur ^ 1) * 32768;
#pragma unroll
      for (int i = 0; i < 8; i++) GLOAD16(g + (size_t)i * 8 * 2048, l + i * 1024);
    }
    const char* LA = smem[cur][0];
    const char* LB = smem[cur][1];
#pragma unroll
    for (int ksl = 0; ksl < 2; ksl++) {
      int kb = (ksl * 64 + koff) ^ sw;
      short8v av[4], bv[4];
#pragma unroll
      for (int ar = 0; ar < 4; ar++) av[ar] = *(const short8v*)(LA + rowA[ar] + kb);
#pragma unroll
      for (int bn = 0; bn < 4; bn++) bv[bn] = *(const short8v*)(LB + rowB[bn] + kb);
#pragma unroll
      for (int ar = 0; ar < 4; ar++)
#pragma unroll
        for (int bn = 0; bn < 4; bn++)
          acc[ar][bn] = __builtin_amdgcn_mfma_f32_16x16x32_bf16(av[ar], bv[bn], acc[ar][bn], 0, 0, 0);
    }
  }

  // ---- epilogue: a*sigmoid(g), register-local pairs (ar, ar+2) ----
#pragma unroll
  for (int q = 0; q < 2; q++) {
    int obase = m0 + (2 * wm + q) * 16 + (lane >> 4) * 4;
    float4 ba = *(const float4*)&b_out[obase];
    float4 bg = *(const float4*)&b_out[1024 + obase];
    float bav[4] = {ba.x, ba.y, ba.z, ba.w};
    float bgv[4] = {bg.x, bg.y, bg.z, bg.w};
#pragma unroll
    for (int bn = 0; bn < 4; bn++) {
      int col = l0 + (wn * 4 + bn) * 16 + (lane & 15);
      float* op = out + ((size_t)b * H_DIM + obase) * L_DIM + col;
#pragma unroll
      for (int r = 0; r < 4; r++) {
        float a_ = acc[q][bn][r] + bav[r];
        float g_ = acc[q + 2][bn][r] + bgv[r];
        op[(size_t)r * L_DIM] = a_ * (1.f / (1.f + expf(-g_)));
      }
    }
  }
}

// ---------------------------------------------------------------------------
extern "C" void kernel_launch(void* const* d_in, const int* in_sizes, int n_in,
                              void* d_out, int out_size, void* d_ws, size_t ws_size,
                              hipStream_t stream) {
  const float* u          = (const float*)d_in[0];
  const float* log_dt     = (const float*)d_in[1];
  const float* C_real     = (const float*)d_in[2];
  const float* log_A_real = (const float*)d_in[3];
  const float* A_imag     = (const float*)d_in[4];
  const float* D          = (const float*)d_in[5];
  const float* W_out      = (const float*)d_in[6];
  const float* b_out      = (const float*)d_in[7];
  float* out = (float*)d_out;

  char* ws = (char*)d_ws;
  float2* wtab = (float2*)(ws + 0);                      // 256 KB
  float2* ctab = (float2*)(ws + (1 << 18));              // 256 KB
  float2* mtab = (float2*)(ws + (1 << 19));              // 1.5 MB
  unsigned short* Wbf = (unsigned short*)(ws + (2 << 20));   // 4 MB
  unsigned short* yws = (unsigned short*)(ws + (8ull << 20));   // 64 MB
  unsigned short* yT  = (unsigned short*)(ws + (76ull << 20));  // 64 MB

  prep_tables<<<128, 256, 0, stream>>>(log_dt, C_real, log_A_real, A_imag, wtab, ctab, mtab);
  prep_w<<<2048, 256, 0, stream>>>(W_out, Wbf);
  scan_kernel<<<B_DIM * H_DIM, 128, 0, stream>>>(u, wtab, ctab, mtab, D, yws);
  transpose_kernel<<<8192, 256, 0, stream>>>(yws, yT);
  gemm_kernel<<<4096, 256, 0, stream>>>(Wbf, yT, b_out, out);
}